// Round 4
// baseline (222.684 us; speedup 1.0000x reference)
//
#include <hip/hip_runtime.h>

#define NUM_ROI 148
#define NN 131072
#define CHUNKS_PER_ROW 4
#define CHUNK (NN / CHUNKS_PER_ROW)      // 32768 floats per block
#define NITER (CHUNK / (256 * 4))        // 32 float4 stores per thread

typedef float vf4 __attribute__((ext_vector_type(4)));

// fillBuffer-shaped writer: 296 output rows (148 r_out + 148 f_out), each row
// split into 4 contiguous 128KB chunks -> 1184 blocks. Each thread stores 32
// sequential float4s (contiguous sweep within the block, like fillBuffer).
// Row index is wave-uniform -> weights via scalar loads; single math path
// (wx = 0 for r-rows) -> zero divergence. Z slice per XCD stays L2-resident
// under round-robin block->XCD mapping (ids differing by 8 share a quarter).
__global__ __launch_bounds__(256) void coconet_kernel(
    const float* __restrict__ X, const float* __restrict__ Z,
    const float* __restrict__ Wr, const float* __restrict__ br,
    const float* __restrict__ Wf, const float* __restrict__ bf,
    float* __restrict__ out)
{
    const int id = blockIdx.x;        // row * 4 + quarter
    const int row = id >> 2;
    const int quarter = id & 3;
    const bool isF = row >= NUM_ROI;
    const int roi = isF ? (row - NUM_ROI) : row;

    float w0, w1, w2, w3, w4, wx, bias;
    if (isF) {
        wx = Wf[roi * 6 + 0];
        w0 = Wf[roi * 6 + 1]; w1 = Wf[roi * 6 + 2]; w2 = Wf[roi * 6 + 3];
        w3 = Wf[roi * 6 + 4]; w4 = Wf[roi * 6 + 5];
        bias = bf[roi];
    } else {
        wx = 0.0f;
        w0 = Wr[roi * 5 + 0]; w1 = Wr[roi * 5 + 1]; w2 = Wr[roi * 5 + 2];
        w3 = Wr[roi * 5 + 3]; w4 = Wr[roi * 5 + 4];
        bias = br[roi];
    }

    const int nb = quarter * CHUNK + threadIdx.x * 4;
    float* op = out + (size_t)row * NN + nb;

    #pragma unroll 4
    for (int it = 0; it < NITER; ++it) {
        const int n = nb + it * 1024;   // 256 threads * 4 floats
        // Z rows n..n+3: 20 contiguous floats (80B, 16B-aligned since n%4==0)
        const vf4* z4 = reinterpret_cast<const vf4*>(Z + (size_t)n * 5);
        const vf4 a = z4[0], b = z4[1], c = z4[2], d = z4[3], e = z4[4];
        const vf4 xv = *reinterpret_cast<const vf4*>(X + n);
        vf4 o;
        o.x = fmaf(a.x,w0, fmaf(a.y,w1, fmaf(a.z,w2, fmaf(a.w,w3, fmaf(b.x,w4, fmaf(xv.x,wx,bias))))));
        o.y = fmaf(b.y,w0, fmaf(b.z,w1, fmaf(b.w,w2, fmaf(c.x,w3, fmaf(c.y,w4, fmaf(xv.y,wx,bias))))));
        o.z = fmaf(c.z,w0, fmaf(c.w,w1, fmaf(d.x,w2, fmaf(d.y,w3, fmaf(d.z,w4, fmaf(xv.z,wx,bias))))));
        o.w = fmaf(d.w,w0, fmaf(e.x,w1, fmaf(e.y,w2, fmaf(e.z,w3, fmaf(e.w,w4, fmaf(xv.w,wx,bias))))));
        __builtin_nontemporal_store(o, reinterpret_cast<vf4*>(op + (size_t)it * 1024));
    }
}

extern "C" void kernel_launch(void* const* d_in, const int* in_sizes, int n_in,
                              void* d_out, int out_size, void* d_ws, size_t ws_size,
                              hipStream_t stream) {
    const float* X  = (const float*)d_in[0];
    const float* Z  = (const float*)d_in[1];
    const float* Wr = (const float*)d_in[2];
    const float* br = (const float*)d_in[3];
    const float* Wf = (const float*)d_in[4];
    const float* bf = (const float*)d_in[5];
    float* out = (float*)d_out;

    const int nblocks = 2 * NUM_ROI * CHUNKS_PER_ROW;  // 1184
    coconet_kernel<<<nblocks, 256, 0, stream>>>(X, Z, Wr, br, Wf, bf, out);
}